// Round 7
// baseline (10976.738 us; speedup 1.0000x reference)
//
#include <hip/hip_runtime.h>
#include <hip/hip_bf16.h>
#include <math.h>

#define BB 64      // batch
#define TT 512     // encoder time
#define NS 128     // decode steps
#define SD 512     // lstm hidden
#define ATT 128
#define NC 64      // num classes
#define KA 1152    // augmented K: 512 in + 512 rec + 64 onehot + 1 bias + 63 pad
#define NBLK 256

typedef __attribute__((ext_vector_type(8))) short bf8;   // 8 bf16
typedef __attribute__((ext_vector_type(4))) float f4;

__device__ __forceinline__ float sigm(float x) { return 1.0f / (1.0f + expf(-x)); }
__device__ __forceinline__ float b2f(short s) {
    union { unsigned u; float f; } c; c.u = ((unsigned)(unsigned short)s) << 16; return c.f;
}
#define MFMA16(a, b, c) __builtin_amdgcn_mfma_f32_16x16x32_bf16((a), (b), (c), 0, 0, 0)

// write-through (agent-scope) store for cross-block data. Readers use PLAIN
// cached loads under the fresh-address discipline: every mutable address is
// written through exactly once and only cached-read after that write.
__device__ __forceinline__ void cstore16(__hip_bfloat16* p, __hip_bfloat16 v) {
    __hip_atomic_store((unsigned short*)p, *(unsigned short*)&v,
                       __ATOMIC_RELAXED, __HIP_MEMORY_SCOPE_AGENT);
}

// ---- per-phase epoch counters (64B-strided lines) ----
__device__ __forceinline__ void arrive(unsigned* ctr) {
    __syncthreads();   // drains vmcnt(0): all block stores visible at coherence point
    if (threadIdx.x == 0)
        __hip_atomic_fetch_add(ctr, 1u, __ATOMIC_RELAXED, __HIP_MEMORY_SCOPE_AGENT);
}
__device__ __forceinline__ void waitc(unsigned* ctr, unsigned target) {
    if (threadIdx.x == 0)
        while (__hip_atomic_load(ctr, __ATOMIC_RELAXED, __HIP_MEMORY_SCOPE_AGENT) < target)
            __builtin_amdgcn_s_sleep(8);
    __syncthreads();
}

// ---------------- fp32 -> bf16 convert (vec4) ----------------
__global__ void f2b_kernel(const float* __restrict__ src, __hip_bfloat16* __restrict__ dst, int n)
{
    int i = (blockIdx.x * blockDim.x + threadIdx.x) * 4;
    if (i < n) {
        float4 v = *(const float4*)(src + i);
        dst[i]     = __hip_bfloat16(v.x);
        dst[i + 1] = __hip_bfloat16(v.y);
        dst[i + 2] = __hip_bfloat16(v.z);
        dst[i + 3] = __hip_bfloat16(v.w);
    }
}

// ---------------- transpose h[b][t][d] -> hT[b][d][t] (bf16) ----------------
__global__ __launch_bounds__(256) void transpose_kernel(const float* __restrict__ h,
                                                        __hip_bfloat16* __restrict__ hT)
{
    __shared__ float tile[64][65];
    int b = blockIdx.x, t0 = blockIdx.y * 64, d0 = blockIdx.z * 64;
#pragma unroll
    for (int k = 0; k < 16; ++k) {
        int lin = k * 256 + threadIdx.x;
        int tt = lin >> 6, dd = lin & 63;
        tile[tt][dd] = h[((size_t)b * TT + t0 + tt) * SD + d0 + dd];
    }
    __syncthreads();
#pragma unroll
    for (int k = 0; k < 16; ++k) {
        int lin = k * 256 + threadIdx.x;
        int dd = lin >> 6, tt = lin & 63;
        hT[((size_t)b * SD + d0 + dd) * TT + t0 + tt] = __hip_bfloat16(tile[tt][dd]);
    }
}

// ---------------- small weights bf16 convert + zero barrier counters ----------------
__global__ void prep_small_kernel(const float* __restrict__ Wphi, const float* __restrict__ Wpsi,
                                  const float* __restrict__ Wcd,
                                  __hip_bfloat16* __restrict__ Wphib, __hip_bfloat16* __restrict__ Wpsib,
                                  __hip_bfloat16* __restrict__ Wcdb, unsigned* __restrict__ barr)
{
    int i = blockIdx.x * 256 + threadIdx.x;
    Wphib[i] = __hip_bfloat16(Wphi[i]);
    Wpsib[i] = __hip_bfloat16(Wpsi[i]);
    Wcdb[i]  = __hip_bfloat16(Wcd[i]);
    if (i < 3 * 128 * 16) barr[i] = 0u;
}

// ---------------- build augmented LSTM weights, gate-interleaved np=4d+q ----------------
__global__ void prep_w_kernel(const float* __restrict__ Wih0, const float* __restrict__ Whh0,
                              const float* __restrict__ bih0, const float* __restrict__ bhh0,
                              const float* __restrict__ Wih1, const float* __restrict__ Whh1,
                              const float* __restrict__ bih1, const float* __restrict__ bhh1,
                              __hip_bfloat16* __restrict__ W1, __hip_bfloat16* __restrict__ W2)
{
    int idx = blockIdx.x * 256 + threadIdx.x;
    const int half = 2048 * KA;
    if (idx >= 2 * half) return;
    int which = idx >= half;
    int id = idx - which * half;
    int np = id / KA, kk = id - np * KA;
    int q = np & 3, d = np >> 2, j = q * 512 + d;
    float v = 0.f;
    if (!which) {
        if (kk < 512)        v = Wih0[j * 576 + 64 + kk];
        else if (kk < 1024)  v = Whh0[j * 512 + kk - 512];
        else if (kk < 1088)  v = Wih0[j * 576 + kk - 1024];
        else if (kk == 1088) v = bih0[j] + bhh0[j];
        W1[id] = __hip_bfloat16(v);
    } else {
        if (kk < 512)        v = Wih1[j * 512 + kk];
        else if (kk < 1024)  v = Whh1[j * 512 + kk - 512];
        else if (kk == 1088) v = bih1[j] + bhh1[j];
        W2[id] = __hip_bfloat16(v);
    }
}

// ---------------- psiT GEMM: psiT[b][a][t'] = Wpsi[a,:]·h[b,t',:] + bpsi[a] ----------------
__global__ __launch_bounds__(256) void psiT_gemm_kernel(
    const __hip_bfloat16* __restrict__ hbf,   // [b*512+t][512]
    const __hip_bfloat16* __restrict__ Wpsib, // [128][512]
    const float* __restrict__ bpsi,
    __hip_bfloat16* __restrict__ psiT)        // [b][a][t']
{
    int lane = threadIdx.x & 63, w = threadIdx.x >> 6;
    int b = blockIdx.x >> 3, at = blockIdx.x & 7;
    int mr = lane & 15, quad = lane >> 4;
    int m0 = at * 16;
    const bf8* Ar = (const bf8*)(Wpsib + (size_t)(m0 + mr) * 512 + quad * 8);
    f4 acc[8] = {};
    for (int k0 = 0; k0 < 512; k0 += 32) {
        int ko = k0 >> 3;
        bf8 a = Ar[ko];
#pragma unroll
        for (int nf = 0; nf < 8; ++nf) {
            const bf8* Br = (const bf8*)(hbf + ((size_t)b * TT + w * 128 + nf * 16 + mr) * 512 + quad * 8);
            acc[nf] = MFMA16(a, Br[ko], acc[nf]);
        }
    }
#pragma unroll
    for (int nf = 0; nf < 8; ++nf) {
#pragma unroll
        for (int r = 0; r < 4; ++r) {
            int a = m0 + quad * 4 + r;
            int tp = w * 128 + nf * 16 + mr;
            psiT[((size_t)b * ATT + a) * TT + tp] = __hip_bfloat16(acc[nf][r] + bpsi[a]);
        }
    }
}

// ---------------- init: X const cols (all t), step-0 state, c ----------------
__global__ void init_kernel(const float* __restrict__ h, const int* __restrict__ x,
                            __hip_bfloat16* __restrict__ Xb1, __hip_bfloat16* __restrict__ Xb2,
                            float* __restrict__ c1, float* __restrict__ c2)
{
    int idx = blockIdx.x * 256 + threadIdx.x;
    const int NA = 128 * 64 * 128;               // const cols, all t
    __hip_bfloat16 zero(0.0f), one(1.0f);
    if (idx < NA) {
        int t = idx >> 13, r = idx & 8191;
        int b = r >> 7, cc = r & 127;
        size_t base = ((size_t)t * BB + b) * KA + 1024 + cc;
        __hip_bfloat16 v1 = (cc < 64) ? ((x[b * NS + t] == cc) ? one : zero)
                                      : ((cc == 64) ? one : zero);
        Xb1[base] = v1;
        Xb2[base] = (cc == 64) ? one : zero;
        return;
    }
    int i2 = idx - NA;
    if (i2 < 32768) {            // X1[0] ctx0 cols 0:512
        int b = i2 >> 9, c = i2 & 511;
        Xb1[(size_t)b * KA + c] = __hip_bfloat16(h[(size_t)b * TT * SD + c]);
        return;
    }
    i2 -= 32768;
    if (i2 < 32768) {            // X1[0] h1 cols 512:1024 = 0
        int b = i2 >> 9, c = i2 & 511;
        Xb1[(size_t)b * KA + 512 + c] = zero;
        return;
    }
    i2 -= 32768;
    if (i2 < 32768) {            // X2[0] h2 cols 512:1024 = 0
        int b = i2 >> 9, c = i2 & 511;
        Xb2[(size_t)b * KA + 512 + c] = zero;
        return;
    }
    i2 -= 32768;
    if (i2 < 32768) { c1[i2] = 0.f; c2[i2] = 0.f; }
}

// ---------------- LSTM phase: wave = 16 rows x full K x 16-batch slice ----------------
__device__ __forceinline__ void lstm_phase(
    const __hip_bfloat16* __restrict__ X,    // [64][1152] fresh-address cached
    const __hip_bfloat16* __restrict__ W,    // [2048][1152] L2-resident
    float* __restrict__ c,
    __hip_bfloat16* dst1, int rs1,
    __hip_bfloat16* dst2, int rs2,
    int bid, int tid)
{
    int lane = tid & 63, w = tid >> 6;
    int mr = lane & 15, quad = lane >> 4;
    int m0 = bid * 16;
    const bf8* Ar = (const bf8*)(W + (size_t)(m0 + mr) * KA + quad * 8);
    const bf8* Br = (const bf8*)(X + (size_t)(w * 16 + mr) * KA + quad * 8);
    f4 acc = {0, 0, 0, 0};
#pragma unroll
    for (int i = 0; i < 36; ++i) {
        bf8 av = Ar[i * 4];
        bf8 bv = Br[i * 4];          // plain cached load (L1 absorbs 16B sub-line reads)
        acc = MFMA16(av, bv, acc);
    }
    // C layout: col=lane&15 -> b within slice; row=quad*4+reg -> np=4d+q
    int d = bid * 4 + quad, b = w * 16 + mr, ci = d * 64 + b;
    float cn = sigm(acc[1]) * c[ci] + sigm(acc[0]) * tanhf(acc[2]);
    float hn = sigm(acc[3]) * tanhf(cn);
    c[ci] = cn;
    __hip_bfloat16 hb(hn);
    cstore16(dst1 + (size_t)b * rs1 + d, hb);
    cstore16(dst2 + (size_t)b * rs2 + d, hb);
}

// ---------------- merged S+C phase (256 blocks = 64 b x 4 d-chunks) ----------------
__device__ __forceinline__ void sc_phase(
    const __hip_bfloat16* __restrict__ scb_ro, // h2 at scb[(b*NS+t)*1024 + 0:512]
    const __hip_bfloat16* __restrict__ Wphib, const float* __restrict__ bphi,
    const __hip_bfloat16* __restrict__ psiT,   // [b][a][t'] read-only
    const __hip_bfloat16* __restrict__ hT,     // [b][d][t'] read-only
    __hip_bfloat16* X1n, __hip_bfloat16* scb, int t,
    float* smem, int bid, int tid)
{
    int b = bid >> 2, dch = bid & 3;
    float* h2s  = smem;          // 512
    float* phis = smem + 512;    // 128
    float* es   = smem + 768;    // 512
    float* red  = smem + 1280;   // 256
    int lane = tid & 63, w = tid >> 6;

    // h2 -> LDS (stride-1, conflict-free)
    {
        const unsigned short* hp = (const unsigned short*)(scb_ro + ((size_t)b * NS + t) * 1024);
        h2s[tid]       = b2f((short)hp[tid]);
        h2s[tid + 256] = b2f((short)hp[tid + 256]);
    }
    __syncthreads();

    // phi[a] = h2 . Wphi[a] + bphi[a];  4 lanes per a-row
    {
        int al = tid & 3;
#pragma unroll
        for (int pass = 0; pass < 2; ++pass) {
            int a = pass * 64 + (tid >> 2);
            const bf8* wr = (const bf8*)(Wphib + (size_t)a * 512 + al * 8);
            float acc = 0.f;
#pragma unroll
            for (int i = 0; i < 16; ++i) {
                bf8 wv = wr[i * 4];
                const float* hp2 = h2s + i * 32 + al * 8;
#pragma unroll
                for (int j = 0; j < 8; ++j) acc += hp2[j] * b2f(wv[j]);
            }
            acc += __shfl_xor(acc, 1);
            acc += __shfl_xor(acc, 2);
            if (al == 0) phis[a] = acc + bphi[a];
        }
    }
    __syncthreads();

    // e[t']: wave w owns t' in [w*128,(w+1)*128), lane -> 2 consecutive t'
    {
        float e0 = 0.f, e1 = 0.f;
        const unsigned short* pp = (const unsigned short*)psiT
                                   + (size_t)b * ATT * TT + w * 128 + lane * 2;
#pragma unroll 4
        for (int a = 0; a < 128; ++a) {
            float pa = phis[a];                          // LDS broadcast
            unsigned v = *(const unsigned*)(pp + (size_t)a * TT);  // 4B coalesced
            e0 += pa * b2f((short)v);
            e1 += pa * b2f((short)(v >> 16));
        }
        es[w * 128 + lane * 2]     = e0;   // stride-2: free
        es[w * 128 + lane * 2 + 1] = e1;
    }
    __syncthreads();

    // softmax over 512 (keep unnormalized es, fold inv into ctx)
    float v0 = es[tid], v1 = es[tid + 256];
    red[tid] = fmaxf(v0, v1);
    __syncthreads();
    for (int st = 128; st > 0; st >>= 1) {
        if (tid < st) red[tid] = fmaxf(red[tid], red[tid + st]);
        __syncthreads();
    }
    float mx = red[0];
    __syncthreads();
    float x0 = expf(v0 - mx), x1 = expf(v1 - mx);
    es[tid] = x0; es[tid + 256] = x1;
    red[tid] = x0 + x1;
    __syncthreads();
    for (int st = 128; st > 0; st >>= 1) {
        if (tid < st) red[tid] += red[tid + st];
        __syncthreads();
    }
    float inv = 1.0f / red[0];
    __syncthreads();

    // ctx[d] = inv * sum_t' es[t'] * hT[b][d][t'], d-chunk of 128
    {
        int d = dch * 128 + (tid >> 1), th = tid & 1;
        const bf8* hp = (const bf8*)(hT + ((size_t)b * SD + d) * TT + th * 256);
        const float* ap = es + th * 256;
        float acc = 0.f;
#pragma unroll
        for (int i = 0; i < 32; ++i) {
            bf8 hv = hp[i];                  // plain cached: L1 absorbs sub-line reads
#pragma unroll
            for (int j = 0; j < 8; ++j) acc += ap[i * 8 + j] * b2f(hv[j]);
        }
        acc += __shfl_xor(acc, 1);
        if (th == 0) {
            __hip_bfloat16 vb(acc * inv);
            cstore16(X1n + (size_t)b * KA + d, vb);
            cstore16(scb + ((size_t)b * NS + t) * 1024 + 512 + d, vb);
        }
    }
}

// ---------------- persistent decode kernel (plain launch, grid=256) ----------------
__global__ __launch_bounds__(256, 1) void decode_kernel(
    const __hip_bfloat16* __restrict__ W1, const __hip_bfloat16* __restrict__ W2,
    const __hip_bfloat16* __restrict__ Wphib, const float* __restrict__ bphi,
    const __hip_bfloat16* __restrict__ psiT, const __hip_bfloat16* __restrict__ hT,
    const __hip_bfloat16* __restrict__ Wcdb, const float* __restrict__ bcd,
    __hip_bfloat16* Xb1, __hip_bfloat16* Xb2,     // [129][64][1152] each
    float* c1, float* c2,
    __hip_bfloat16* scb, float* out, unsigned* barr)
{
    __shared__ float smem[4096];
    int bid = blockIdx.x, tid = threadIdx.x;
    const bool is_lstm = bid < 128;
    // counters: barL0[t] = barr[t*16]; barL1[t] = barr[(128+t)*16]; barSC[t] = barr[(256+t)*16]

    for (int t = 0; t < NS; ++t) {
        __hip_bfloat16* X1  = Xb1 + (size_t)t * BB * KA;
        __hip_bfloat16* X2  = Xb2 + (size_t)t * BB * KA;
        __hip_bfloat16* X1n = Xb1 + (size_t)(t + 1) * BB * KA;
        __hip_bfloat16* X2n = Xb2 + (size_t)(t + 1) * BB * KA;

        if (is_lstm) {
            if (t > 0) waitc(barr + (256 + t - 1) * 16, 256);   // ctx@t-1 done
            lstm_phase(X1, W1, c1, X2, KA, X1n + 512, KA, bid, tid);
            arrive(barr + t * 16);
            waitc(barr + t * 16, 128);                          // h1@t done
            lstm_phase(X2, W2, c2, X2n + 512, KA, scb + (size_t)t * 1024, NS * 1024, bid, tid);
            arrive(barr + (128 + t) * 16);
        }
        waitc(barr + (128 + t) * 16, 128);                      // h2@t done
        sc_phase(scb, Wphib, bphi, psiT, hT, X1n, scb, t, smem, bid, tid);
        arrive(barr + (256 + t) * 16);
    }
    waitc(barr + (256 + 127) * 16, 256);

    // ---- output projection: out = scb @ Wcd^T + bcd ----
    int lane = tid & 63, w = tid >> 6;
    int gw = bid * 4 + w;
    if (gw < 512) {
        int mr = lane & 15, quad = lane >> 4;
        int m0 = gw * 16;
        const bf8* Ar = (const bf8*)(scb + (size_t)(m0 + mr) * 1024 + quad * 8);
        f4 acc[4] = {};
        for (int k0 = 0; k0 < 1024; k0 += 32) {
            int ko = k0 >> 3;
            bf8 a = Ar[ko];
#pragma unroll
            for (int nf = 0; nf < 4; ++nf) {
                const bf8* Br = (const bf8*)(Wcdb + (size_t)(nf * 16 + mr) * 1024 + quad * 8);
                acc[nf] = MFMA16(a, Br[ko], acc[nf]);
            }
        }
#pragma unroll
        for (int nf = 0; nf < 4; ++nf) {
            int n = nf * 16 + mr;
            float bs = bcd[n];
#pragma unroll
            for (int r = 0; r < 4; ++r)
                out[(size_t)(m0 + quad * 4 + r) * 64 + n] = acc[nf][r] + bs;
        }
    }
}

extern "C" void kernel_launch(void* const* d_in, const int* in_sizes, int n_in,
                              void* d_out, int out_size, void* d_ws, size_t ws_size,
                              hipStream_t stream)
{
    const int*   x    = (const int*)  d_in[0];
    const float* h    = (const float*)d_in[1];
    const float* Wih0 = (const float*)d_in[2];
    const float* Whh0 = (const float*)d_in[3];
    const float* bih0 = (const float*)d_in[4];
    const float* bhh0 = (const float*)d_in[5];
    const float* Wih1 = (const float*)d_in[6];
    const float* Whh1 = (const float*)d_in[7];
    const float* bih1 = (const float*)d_in[8];
    const float* bhh1 = (const float*)d_in[9];
    const float* Wphi = (const float*)d_in[10];
    const float* bphi = (const float*)d_in[11];
    const float* Wpsi = (const float*)d_in[12];
    const float* bpsi = (const float*)d_in[13];
    const float* Wcd  = (const float*)d_in[14];
    const float* bcd  = (const float*)d_in[15];
    float* out = (float*)d_out;

    char* p = (char*)d_ws;
    __hip_bfloat16* hT    = (__hip_bfloat16*)p; p += (size_t)BB * SD * TT * 2;     // 33.55 MB
    __hip_bfloat16* psiT  = (__hip_bfloat16*)p; p += (size_t)BB * ATT * TT * 2;    // 8.39 MB
    __hip_bfloat16* scbf  = (__hip_bfloat16*)p; p += (size_t)BB * NS * 1024 * 2;   // 16.78 MB
    __hip_bfloat16* W1aug = (__hip_bfloat16*)p; p += (size_t)2048 * KA * 2;        // 4.72 MB
    __hip_bfloat16* W2aug = (__hip_bfloat16*)p; p += (size_t)2048 * KA * 2;        // 4.72 MB
    __hip_bfloat16* Wphib = (__hip_bfloat16*)p; p += (size_t)ATT * SD * 2;
    __hip_bfloat16* Wpsib = (__hip_bfloat16*)p; p += (size_t)ATT * SD * 2;
    __hip_bfloat16* Wcdb  = (__hip_bfloat16*)p; p += (size_t)NC * 1024 * 2;
    float* c1    = (float*)p; p += (size_t)SD * BB * 4;
    float* c2    = (float*)p; p += (size_t)SD * BB * 4;
    unsigned* barr = (unsigned*)p; p += 3 * 128 * 16 * 4;                          // 24 KB
    __hip_bfloat16* Xb1 = (__hip_bfloat16*)p; p += (size_t)129 * BB * KA * 2;      // 19.02 MB
    __hip_bfloat16* Xb2 = (__hip_bfloat16*)p; p += (size_t)129 * BB * KA * 2;      // 19.02 MB
    // hbf (33.55 MB) aliases Xb1+Xb2 (38 MB): used only before init overwrites (stream-ordered)
    __hip_bfloat16* hbf = Xb1;

    // ---- prep ----
    f2b_kernel<<<16384, 256, 0, stream>>>(h, hbf, BB * TT * SD);
    transpose_kernel<<<dim3(64, 8, 8), 256, 0, stream>>>(h, hT);
    prep_small_kernel<<<256, 256, 0, stream>>>(Wphi, Wpsi, Wcd, Wphib, Wpsib, Wcdb, barr);
    prep_w_kernel<<<18432, 256, 0, stream>>>(Wih0, Whh0, bih0, bhh0,
                                             Wih1, Whh1, bih1, bhh1, W1aug, W2aug);
    psiT_gemm_kernel<<<512, 256, 0, stream>>>(hbf, Wpsib, bpsi, psiT);
    init_kernel<<<4608, 256, 0, stream>>>(h, x, Xb1, Xb2, c1, c2);

    // ---- persistent decode (plain launch; 256 blocks, >=2 blocks/CU capacity) ----
    decode_kernel<<<NBLK, 256, 0, stream>>>(
        W1aug, W2aug, Wphib, bphi, psiT, hT, Wcdb, bcd,
        Xb1, Xb2, c1, c2, scbf, out, barr);
}